// Round 13
// baseline (281.423 us; speedup 1.0000x reference)
//
#include <hip/hip_runtime.h>
#include <math.h>

#define NN 20000
#define EE 320000
#define FF 128
#define HH 256
#define MT 64        // edges per block (4 blocks/CU phase diversity)
#define NTILE 5000   // EE / MT exactly; 5000 = 8 * 625 -> clean XCD swizzle

typedef _Float16 f16x8 __attribute__((ext_vector_type(8)));
typedef _Float16 f16x4 __attribute__((ext_vector_type(4)));
typedef float    f32x4  __attribute__((ext_vector_type(4)));
typedef float    f32x16 __attribute__((ext_vector_type(16)));

// Conflict-free LDS: 64 rows x 512 B (row stride == 0 mod 32 banks), 16-B chunk
// XOR swizzle by (row&31) — 5 bits so the 32x32 af-read (32 rows/hf at one
// logical chunk) spreads over all 32 chunk slots (balanced b128 floor).
// Gather/h2/fp32/segred bank classes (byte bits 4-6) identical to the 3-bit
// swizzle measured in r12.
#define HADDR(m, bcol) (((m) << 9) + ((bcol) ^ (((m) & 31) << 4)))

// ---- workspace layout (bytes) ----
// cnt   : NN i32        @ 0
// wptr  : NN i32        @ 80,000
// spair : EE u32        @ 160,000      (src | dst<<16)
// w2f   : 8192 frags    @ 6,560,000    (32x32-frag-major W2 f16, 131072 B)
// w3f   : 4096 frags    @ 6,691,072    (32x32-frag-major W3 f16,  65536 B)
// wcf   : 8192 frags    @ 6,756,608    (16x16-frag-major [W1a-W1b ; W1b] f16)
// PQ    : NN*512 f16    @ 6,887,680    (P' | Q' per node) end 27,367,680
// NOTE: K-loop W prefetch intentionally over-reads one ks past w2f/w3f ends ->
// lands in the adjacent workspace region (mapped, value unused).
#define WPTR_OFF  80000
#define SPAIR_OFF 160000
#define W2F_OFF   6560000
#define W3F_OFF   6691072
#define WCF_OFF   6756608
#define PQ_OFF    6887680

// prep roles (blocks of 256 threads)
#define PB_HIST 1250   // 320,000 hist atomics
#define PB_W2   32     // 8192 fragments
#define PB_WC   32     // 8192 fragments
#define PB_W3   16     // 4096 fragments
#define PREP_BLOCKS (PB_HIST + PB_W2 + PB_WC + PB_W3)

#define NODEB 625      // 20000/32 exactly; block NODEB is the scan block

// 32x32x16 fragment-major (w2f/w3f):
//   entry f = (nt*16 + ks)*64 + lane; elem (n,k): n = nt*32 + (lane&31),
//   k = ks*16 + (lane>>5)*8 + j  (j=0..7).  [r6-verified layout]
// 16x16x32 fragment-major (wcf): f = (nt*KB + kb)*64 + lane;
//   n = nt*16 + (lane&15), k = kb*32 + (lane>>4)*8 + j.

__global__ __launch_bounds__(256) void prep_kernel(
    const int* __restrict__ eidx,
    const float* __restrict__ W1, const float* __restrict__ W2,
    const float* __restrict__ W3,
    _Float16* __restrict__ w2f, _Float16* __restrict__ wcf,
    _Float16* __restrict__ w3f, int* __restrict__ cnt)
{
    const int b = blockIdx.x, t = threadIdx.x;
    if (b < PB_HIST) {                                  // dst histogram
        const int e = b * 256 + t;
        atomicAdd(&cnt[eidx[EE + e]], 1);
    } else if (b < PB_HIST + PB_W2) {                   // W2 fragments (32x32, 16 ks)
        const int f = (b - PB_HIST) * 256 + t;                      // 0..8191
        const int n = ((f >> 10) << 5) | (f & 31);                  // 0..255
        const int k = (((f >> 6) & 15) << 4) | (((f >> 5) & 1) << 3);
        const float* s = W2 + (size_t)n * HH + k;
        _Float16 o[8];
        #pragma unroll
        for (int j = 0; j < 8; ++j) o[j] = (_Float16)s[j];
        __builtin_memcpy(w2f + (size_t)f * 8, o, 16);
    } else if (b < PB_HIST + PB_W2 + PB_WC) {           // Wc fragments (16x16, KB=4)
        const int f = (b - (PB_HIST + PB_W2)) * 256 + t;            // 0..8191
        const int n = ((f >> 8) << 4) | (f & 15);                   // 0..511
        const int k = (((f >> 6) & 3) << 5) | (((f >> 4) & 3) << 3);// 0..127
        _Float16 o[8];
        if (n < HH) {        // rows 0..255: W1a - W1b (multiplies x[dst])
            const float* a = W1 + (size_t)n * HH + k;
            #pragma unroll
            for (int j = 0; j < 8; ++j) o[j] = (_Float16)(a[j] - a[FF + j]);
        } else {             // rows 256..511: W1b (multiplies x[src])
            const float* a = W1 + (size_t)(n - HH) * HH + FF + k;
            #pragma unroll
            for (int j = 0; j < 8; ++j) o[j] = (_Float16)a[j];
        }
        __builtin_memcpy(wcf + (size_t)f * 8, o, 16);
    } else {                                            // W3 fragments (32x32, 16 ks)
        const int f = (b - (PB_HIST + PB_W2 + PB_WC)) * 256 + t;    // 0..4095
        const int n = ((f >> 10) << 5) | (f & 31);                  // 0..127
        const int k = (((f >> 6) & 15) << 4) | (((f >> 5) & 1) << 3);
        const float* s = W3 + (size_t)n * HH + k;
        _Float16 o[8];
        #pragma unroll
        for (int j = 0; j < 8; ++j) o[j] = (_Float16)s[j];
        __builtin_memcpy(w3f + (size_t)f * 8, o, 16);
    }
}

// Node precompute: PQ'[i][0:256] = s1*(x@(W1a-W1b)^T) + c1 ; PQ'[i][256:512] = s1*(x@W1b^T)
// 32 nodes/block (625 blocks exactly covers NN); block NODEB is the scan block.
__global__ __launch_bounds__(512) void node_kernel(
    const float* __restrict__ x, const _Float16* __restrict__ wcf,
    const float* __restrict__ b1, const float* __restrict__ g1,
    const float* __restrict__ be1, const float* __restrict__ rm1,
    const float* __restrict__ rv1,
    _Float16* __restrict__ PQ,
    const int* __restrict__ cnt, int* __restrict__ wptr)
{
    if (blockIdx.x == NODEB) {   // exclusive prefix sum cnt -> wptr
        __shared__ int sp[512];
        const int t = threadIdx.x;
        const int base = t * 40;                  // 512*40 = 20480 >= NN
        int s = 0;
        #pragma unroll 1
        for (int g = 0; g < 5; ++g) {
            int v[8];
            #pragma unroll
            for (int u = 0; u < 8; ++u) {
                const int idx = base + g * 8 + u;
                v[u] = (idx < NN) ? cnt[idx] : 0;
            }
            #pragma unroll
            for (int u = 0; u < 8; ++u) s += v[u];
        }
        sp[t] = s;
        __syncthreads();
        for (int d = 1; d < 512; d <<= 1) {
            const int v = (t >= d) ? sp[t - d] : 0;
            __syncthreads();
            sp[t] += v;
            __syncthreads();
        }
        int run = sp[t] - s;
        #pragma unroll 1
        for (int g = 0; g < 5; ++g) {
            int v[8];
            #pragma unroll
            for (int u = 0; u < 8; ++u) {
                const int idx = base + g * 8 + u;
                v[u] = (idx < NN) ? cnt[idx] : 0;
            }
            #pragma unroll
            for (int u = 0; u < 8; ++u) {
                const int idx = base + g * 8 + u;
                if (idx < NN) { wptr[idx] = run; run += v[u]; }
            }
        }
        return;
    }

    const int tid = threadIdx.x;
    const int lane = tid & 63, wv = tid >> 6;     // wave owns 64 output channels
    const int lr = lane & 15, lq = lane >> 4;
    const int node0 = blockIdx.x * 32;            // 625 * 32 == 20000 exactly

    f32x4 acc[2][4];
    #pragma unroll
    for (int i = 0; i < 2; ++i)
        #pragma unroll
        for (int j = 0; j < 4; ++j) acc[i][j] = (f32x4){0.f, 0.f, 0.f, 0.f};

    const f16x8* wb = (const f16x8*)wcf + (size_t)(wv * 16) * 64 + lane;
    #pragma unroll 1
    for (int kb = 0; kb < 4; ++kb) {
        f16x8 wf[4], af[2];
        #pragma unroll
        for (int j = 0; j < 4; ++j) wf[j] = wb[(j * 4 + kb) * 64];
        #pragma unroll
        for (int i = 0; i < 2; ++i) {
            const int nd = node0 + i * 16 + lr;   // always < NN (exact tiling)
            const float* xp = x + (size_t)nd * FF + kb * 32 + lq * 8;
            const float4 xa = *(const float4*)xp;
            const float4 xb = *(const float4*)(xp + 4);
            f16x8 a;
            a[0] = (_Float16)xa.x; a[1] = (_Float16)xa.y;
            a[2] = (_Float16)xa.z; a[3] = (_Float16)xa.w;
            a[4] = (_Float16)xb.x; a[5] = (_Float16)xb.y;
            a[6] = (_Float16)xb.z; a[7] = (_Float16)xb.w;
            af[i] = a;
        }
        #pragma unroll
        for (int i = 0; i < 2; ++i)
            #pragma unroll
            for (int j = 0; j < 4; ++j)   // swapped operands: lane holds 4 consecutive n
                acc[i][j] = __builtin_amdgcn_mfma_f32_16x16x32_f16(wf[j], af[i], acc[i][j], 0, 0, 0);
    }

    #pragma unroll
    for (int j = 0; j < 4; ++j) {
        const int n0 = wv * 64 + j * 16 + lq * 4;
        const int ch = (n0 < HH) ? n0 : n0 - HH;
        float sc[4], cc[4];
        #pragma unroll
        for (int r = 0; r < 4; ++r) {
            const float s1 = g1[ch + r] * rsqrtf(rv1[ch + r] + 1e-5f);
            sc[r] = s1;
            cc[r] = (n0 < HH) ? (b1[ch + r] - rm1[ch + r]) * s1 + be1[ch + r] : 0.f;
        }
        #pragma unroll
        for (int i = 0; i < 2; ++i) {
            const int nd = node0 + i * 16 + lr;
            f16x4 o;
            #pragma unroll
            for (int r = 0; r < 4; ++r) o[r] = (_Float16)(acc[i][j][r] * sc[r] + cc[r]);
            *(f16x4*)(PQ + (size_t)nd * 512 + n0) = o;
        }
    }
}

// scatter + zero-out (out must be zero before fused's atomics; folded here)
__global__ __launch_bounds__(256) void scatter_kernel(const int* __restrict__ eidx,
                                                      int* __restrict__ wptr,
                                                      unsigned int* __restrict__ spair,
                                                      float* __restrict__ outp)
{
    const int idx = blockIdx.x * 256 + threadIdx.x;
    float4* o4 = (float4*)outp;
    #pragma unroll
    for (int i = 0; i < 2; ++i)
        o4[idx + i * 320000] = (float4){0.f, 0.f, 0.f, 0.f};   // 640000 float4 total
    if (idx < EE) {
        const int d = eidx[EE + idx];
        const int pos = atomicAdd(&wptr[d], 1);
        spair[pos] = (unsigned int)eidx[idx] | ((unsigned int)d << 16);
    }
}

// 256 threads (4 waves), MT=64, ~35 KB LDS -> 4 blocks/CU.
// Stages 2/3 use 32x32x16 MFMA (2x FLOP/instr at 8.07cy vs 4.85 -> -17% MFMA
// issue; one af b128 feeds 4 MFMAs -> stage-2 LDS reads halved vs 16x16).
// W2 read 2x/block, W3 2x/block, both 1-deep prefetched (r6's regression
// causes — 4x traffic, no prefetch — both fixed here).
__global__ __launch_bounds__(256, 4) void fused_edge_mlp(
    const _Float16* __restrict__ PQ,
    const unsigned int* __restrict__ spair,
    const _Float16* __restrict__ W2f,
    const float* __restrict__ b2, const float* __restrict__ g2,
    const float* __restrict__ be2, const float* __restrict__ rm2,
    const float* __restrict__ rv2,
    const _Float16* __restrict__ W3f,
    float* __restrict__ outp)
{
    __shared__ __align__(16) char shb[MT * 512];   // 32 KiB: f16 [64][256] / fp32 [64][128]
    __shared__ __align__(16) float s_scale[HH];
    __shared__ __align__(16) float s_c[HH];
    __shared__ int s_dst[MT];
    // total LDS ~ 35 KB -> 4 blocks/CU

    const int tid = threadIdx.x;
    const int lane = tid & 63, wv = tid >> 6;     // wv 0..3
    const int lr = lane & 15, lq = lane >> 4;
    const int l5 = lane & 31, hf = lane >> 5;     // 32x32 fragment coords

    // bijective XCD swizzle (5000 = 8*625 exactly)
    const int swz = (blockIdx.x & 7) * 625 + (blockIdx.x >> 3);
    const int e0 = swz * MT;

    // ---- gather: h1 = relu(P'[dst] + Q'[src]) -> swizzled f16 [64][256]
    {
        const int r = wv * 16 + lr;               // 0..63
        const int q = lq;
        const unsigned int pv = spair[e0 + r];
        const int dr = (int)(pv >> 16), sr = (int)(pv & 0xffffu);
        const f16x8* pd = (const f16x8*)(PQ + (size_t)dr * 512 + q * 64);
        const f16x8* ps = (const f16x8*)(PQ + (size_t)sr * 512 + 256 + q * 64);
        f16x8 av[8], bv[8];
        #pragma unroll
        for (int i = 0; i < 8; ++i) av[i] = pd[i];        // issue all 16 loads up front
        #pragma unroll
        for (int i = 0; i < 8; ++i) bv[i] = ps[i];

        if (tid < MT) s_dst[tid] = (int)(spair[e0 + tid] >> 16);
        {   // tid covers 0..255 == HH
            const float sc = g2[tid] * rsqrtf(rv2[tid] + 1e-5f);
            s_scale[tid] = sc;
            s_c[tid] = (b2[tid] - rm2[tid]) * sc + be2[tid];
        }

        #pragma unroll
        for (int i = 0; i < 8; ++i) {
            f16x8 s = av[i] + bv[i];                      // v_pk_add_f16
            f16x8 o;
            #pragma unroll
            for (int j = 0; j < 8; ++j) {
                const _Float16 z = (_Float16)0;
                o[j] = s[j] > z ? s[j] : z;               // v_pk_max_f16
            }
            *(f16x8*)(shb + HADDR(r, q * 128 + i * 16)) = o;
        }
    }
    __syncthreads();

    {   // ---- stage 2 (32x32x16): h2 = relu(s2*(h1 @ W2^T) + c2), in place; 2m x 2n
        // wave = 32 rows x 128 cols: one af b128 read feeds 4 MFMAs; W2 2x/block.
        const int wm = wv >> 1, wn = wv & 1;
        const int m = wm * 32 + l5;
        f32x16 acc[4];
        const f32x16 zz = {};
        #pragma unroll
        for (int j = 0; j < 4; ++j) acc[j] = zz;

        const f16x8* wbase = (const f16x8*)W2f + lane;
        f16x8 cw[4];
        #pragma unroll
        for (int j = 0; j < 4; ++j) cw[j] = wbase[((wn * 4 + j) * 16) * 64];
        __builtin_amdgcn_s_setprio(1);
        #pragma unroll 1
        for (int ks = 0; ks < 16; ++ks) {
            f16x8 nw[4];                                   // prefetch next ks (last over-reads into w3f: harmless)
            #pragma unroll
            for (int j = 0; j < 4; ++j) nw[j] = wbase[((wn * 4 + j) * 16 + ks + 1) * 64];
            const f16x8 bf = *(const f16x8*)(shb + HADDR(m, ks * 32 + hf * 16));
            #pragma unroll
            for (int j = 0; j < 4; ++j)
                acc[j] = __builtin_amdgcn_mfma_f32_32x32x16_f16(cw[j], bf, acc[j], 0, 0, 0);
            #pragma unroll
            for (int j = 0; j < 4; ++j) cw[j] = nw[j];
        }
        __builtin_amdgcn_s_setprio(0);
        __syncthreads();   // all reads of h1 done -> safe to overwrite in place
        // Swapped 32x32 C-layout (r6-verified): edge row = m; channel within tile
        // = (reg&3) + 8*(reg>>2) + 4*hf -> 4 packed f16 per (j,grp).
        #pragma unroll
        for (int j = 0; j < 4; ++j) {
            const int ntile = wn * 4 + j;
            #pragma unroll
            for (int grp = 0; grp < 4; ++grp) {
                const int n0 = ntile * 32 + grp * 8 + hf * 4;
                const float4 sc4 = *(const float4*)&s_scale[n0];
                const float4 cc4 = *(const float4*)&s_c[n0];
                f16x4 o;
                o[0] = (_Float16)fmaxf(acc[j][grp * 4 + 0] * sc4.x + cc4.x, 0.f);
                o[1] = (_Float16)fmaxf(acc[j][grp * 4 + 1] * sc4.y + cc4.y, 0.f);
                o[2] = (_Float16)fmaxf(acc[j][grp * 4 + 2] * sc4.z + cc4.z, 0.f);
                o[3] = (_Float16)fmaxf(acc[j][grp * 4 + 3] * sc4.w + cc4.w, 0.f);
                *(f16x4*)(shb + HADDR(m, n0 * 2)) = o;    // packed 8 B store
            }
        }
        __syncthreads();
    }

    {   // ---- stage 3 (32x32x16): [64x256] @ W3^T -> fp32 tile -> segmented scatter-add
        // wave = 32 rows x 64 cols; W3 2x/block, prefetched.
        const int wm = wv >> 1, wn = wv & 1;
        const int m = wm * 32 + l5;
        f32x16 acc[2];
        const f32x16 zz = {};
        acc[0] = zz; acc[1] = zz;

        const f16x8* wbase = (const f16x8*)W3f + lane;
        f16x8 cw[2];
        #pragma unroll
        for (int j = 0; j < 2; ++j) cw[j] = wbase[((wn * 2 + j) * 16) * 64];
        __builtin_amdgcn_s_setprio(1);
        #pragma unroll 1
        for (int ks = 0; ks < 16; ++ks) {
            f16x8 nw[2];                                   // last iter over-reads into wcf: harmless
            #pragma unroll
            for (int j = 0; j < 2; ++j) nw[j] = wbase[((wn * 2 + j) * 16 + ks + 1) * 64];
            const f16x8 bf = *(const f16x8*)(shb + HADDR(m, ks * 32 + hf * 16));
            #pragma unroll
            for (int j = 0; j < 2; ++j)
                acc[j] = __builtin_amdgcn_mfma_f32_32x32x16_f16(cw[j], bf, acc[j], 0, 0, 0);
            #pragma unroll
            for (int j = 0; j < 2; ++j) cw[j] = nw[j];
        }
        __builtin_amdgcn_s_setprio(0);
        __syncthreads();   // K-loop reads done before fp32 reuse of shb
        #pragma unroll
        for (int j = 0; j < 2; ++j) {
            const int ntile = wn * 2 + j;
            #pragma unroll
            for (int grp = 0; grp < 4; ++grp) {
                const int n0 = ntile * 32 + grp * 8 + hf * 4;     // multiple of 4
                f32x4 o = { acc[j][grp * 4 + 0], acc[j][grp * 4 + 1],
                            acc[j][grp * 4 + 2], acc[j][grp * 4 + 3] };
                *(f32x4*)(shb + HADDR(m, n0 * 4)) = o;    // packed 16 B store
            }
        }
        __syncthreads();

        {   // sorted dst -> one atomic per (segment, col, chunk); batched loads
            const int col = tid & 127;                    // 0..127
            const int bc  = col * 4;
            const int r0  = (tid >> 7) * 32;              // 0 or 32
            int cur = s_dst[r0];
            float run = 0.f;
            #pragma unroll 1
            for (int g = 0; g < 4; ++g) {
                float v[8];
                #pragma unroll
                for (int u = 0; u < 8; ++u)
                    v[u] = *(const float*)(shb + HADDR(r0 + g * 8 + u, bc));
                #pragma unroll
                for (int u = 0; u < 8; ++u) {
                    const int r = r0 + g * 8 + u;
                    const int d = s_dst[r];              // wave-uniform
                    if (d != cur) {
                        atomicAdd(&outp[(size_t)cur * FF + col], run);
                        run = 0.f; cur = d;
                    }
                    run += v[u];
                }
            }
            atomicAdd(&outp[(size_t)cur * FF + col], run);
        }
    }
}

__global__ __launch_bounds__(256) void finalize_kernel(const int* __restrict__ cnt,
                                                       const float* __restrict__ b3,
                                                       float* __restrict__ out)
{
    const int i4 = (blockIdx.x * 256 + threadIdx.x) * 4;
    if (i4 < NN * FF) {
        const float c = fmaxf((float)cnt[i4 >> 7], 1.0f);   // 4 | 128 -> same node for all 4
        const float rc = 1.0f / c;
        float4 v = *(const float4*)(out + i4);
        const float* bb = b3 + (i4 & 127);
        v.x = tanhf(v.x * rc + bb[0]);
        v.y = tanhf(v.y * rc + bb[1]);
        v.z = tanhf(v.z * rc + bb[2]);
        v.w = tanhf(v.w * rc + bb[3]);
        *(float4*)(out + i4) = v;
    }
}

extern "C" void kernel_launch(void* const* d_in, const int* in_sizes, int n_in,
                              void* d_out, int out_size, void* d_ws, size_t ws_size,
                              hipStream_t stream)
{
    const float* x   = (const float*)d_in[0];
    const int*   ei  = (const int*)d_in[1];
    const float* W1  = (const float*)d_in[2];
    const float* b1  = (const float*)d_in[3];
    const float* g1  = (const float*)d_in[4];
    const float* be1 = (const float*)d_in[5];
    const float* rm1 = (const float*)d_in[6];
    const float* rv1 = (const float*)d_in[7];
    const float* W2  = (const float*)d_in[8];
    const float* b2  = (const float*)d_in[9];
    const float* g2  = (const float*)d_in[10];
    const float* be2 = (const float*)d_in[11];
    const float* rm2 = (const float*)d_in[12];
    const float* rv2 = (const float*)d_in[13];
    const float* W3  = (const float*)d_in[14];
    const float* b3  = (const float*)d_in[15];

    char* ws = (char*)d_ws;
    int* cnt_i = (int*)ws;
    int* wptr  = (int*)(ws + WPTR_OFF);
    unsigned int* spair = (unsigned int*)(ws + SPAIR_OFF);
    _Float16* w2f = (_Float16*)(ws + W2F_OFF);
    _Float16* w3f = (_Float16*)(ws + W3F_OFF);
    _Float16* wcf = (_Float16*)(ws + WCF_OFF);
    _Float16* PQ  = (_Float16*)(ws + PQ_OFF);
    float* outp = (float*)d_out;

    hipMemsetAsync(cnt_i, 0, NN * sizeof(int), stream);

    prep_kernel<<<PREP_BLOCKS, 256, 0, stream>>>(ei, W1, W2, W3,
                                                 w2f, wcf, w3f, cnt_i);
    node_kernel<<<NODEB + 1, 512, 0, stream>>>(x, wcf, b1, g1, be1, rm1, rv1,
                                               PQ, cnt_i, wptr);
    scatter_kernel<<<(EE + 255) / 256, 256, 0, stream>>>(ei, wptr, spair, outp);
    fused_edge_mlp<<<NTILE, 256, 0, stream>>>(PQ, spair,
                                              w2f, b2, g2, be2, rm2, rv2,
                                              w3f, outp);
    finalize_kernel<<<(NN * FF / 4 + 255) / 256, 256, 0, stream>>>(cnt_i, b3, outp);
}

// Round 14
// 260.430 us; speedup vs baseline: 1.0806x; 1.0806x over previous
//
#include <hip/hip_runtime.h>
#include <math.h>

#define NN 20000
#define EE 320000
#define FF 128
#define HH 256
#define MT 64        // edges per block (4 blocks/CU phase diversity)
#define NTILE 5000   // EE / MT exactly; 5000 = 8 * 625 -> clean XCD swizzle

typedef _Float16 f16x8 __attribute__((ext_vector_type(8)));
typedef _Float16 f16x4 __attribute__((ext_vector_type(4)));
typedef float    f32x4 __attribute__((ext_vector_type(4)));

// Conflict-free LDS: 64 rows x 512 B (row stride == 0 mod 32 banks), 16-B chunk
// XOR swizzle by (row&7).  [r12-measured optimum]
#define HADDR(m, bcol) (((m) << 9) + ((bcol) ^ (((m) & 7) << 4)))

// ---- workspace layout (bytes) ----
// cnt   : NN i32        @ 0
// wptr  : NN i32        @ 80,000
// spair : EE u32        @ 160,000      (src | dst<<16)
// c2p   : HH f32        @ 1,500,000    (folded BN bias for stage 2, 1 KB)
// w2f   : 8192 frags    @ 6,560,000    (16x16-frag-major s2-scaled W2 f16, KB=8)
// w3f   : 4096 frags    @ 6,691,072    (16x16-frag-major W3 f16, KB=8)
// wcf   : 8192 frags    @ 6,756,608    (16x16-frag-major [W1a-W1b ; W1b] f16)
// PQ    : NN*512 f16    @ 6,887,680    (P' | Q' per node) end 27,367,680
// NOTE: K-loop W prefetch intentionally over-reads one kb past w2f/w3f ends ->
// lands in the adjacent workspace region (mapped, value unused).
#define WPTR_OFF  80000
#define SPAIR_OFF 160000
#define C2P_OFF   1500000
#define W2F_OFF   6560000
#define W3F_OFF   6691072
#define WCF_OFF   6756608
#define PQ_OFF    6887680

// prep roles (blocks of 256 threads)
#define PB_HIST 1250   // 320,000 hist atomics
#define PB_W2   32     // 8192 fragments (s2-scaled)
#define PB_WC   32     // 8192 fragments
#define PB_W3   16     // 4096 fragments
#define PREP_BLOCKS (PB_HIST + PB_W2 + PB_WC + PB_W3)

#define NODEB 625      // 20000/32 exactly; block NODEB is the scan block

// 16x16x32 fragment-major layout (all weight buffers):
//   frag f = (nt*8 + kb)*64 + lane, lane = lq*16 + lr
//   element (n, k): n = nt*16 + lr, k = kb*32 + lq*8 + j (j = 0..7)
// A wave's 64 lanes read frags[f0 + lane] -> one contiguous 1 KiB transaction.

__global__ __launch_bounds__(256) void prep_kernel(
    const int* __restrict__ eidx,
    const float* __restrict__ W1, const float* __restrict__ W2,
    const float* __restrict__ W3,
    const float* __restrict__ b2, const float* __restrict__ g2,
    const float* __restrict__ be2, const float* __restrict__ rm2,
    const float* __restrict__ rv2,
    _Float16* __restrict__ w2f, _Float16* __restrict__ wcf,
    _Float16* __restrict__ w3f, int* __restrict__ cnt,
    float* __restrict__ c2p)
{
    const int b = blockIdx.x, t = threadIdx.x;
    if (b < PB_HIST) {                                  // dst histogram
        const int e = b * 256 + t;
        atomicAdd(&cnt[eidx[EE + e]], 1);
    } else if (b < PB_HIST + PB_W2) {                   // s2-scaled W2 fragments (KB=8)
        const int f = (b - PB_HIST) * 256 + t;                      // 0..8191
        const int n = ((f >> 9) << 4) | (f & 15);                   // 0..255
        const int k = (((f >> 6) & 7) << 5) | (((f >> 4) & 3) << 3);
        const float s2n = g2[n] * rsqrtf(rv2[n] + 1e-5f);
        const float* s = W2 + (size_t)n * HH + k;
        _Float16 o[8];
        #pragma unroll
        for (int j = 0; j < 8; ++j) o[j] = (_Float16)(s2n * s[j]);
        __builtin_memcpy(w2f + (size_t)f * 8, o, 16);
        if (b == PB_HIST) {   // first W2 block also emits the folded bias vector
            const float s2t = g2[t] * rsqrtf(rv2[t] + 1e-5f);
            c2p[t] = (b2[t] - rm2[t]) * s2t + be2[t];
        }
    } else if (b < PB_HIST + PB_W2 + PB_WC) {           // Wc fragments (KB=4)
        const int f = (b - (PB_HIST + PB_W2)) * 256 + t;            // 0..8191
        const int n = ((f >> 8) << 4) | (f & 15);                   // 0..511
        const int k = (((f >> 6) & 3) << 5) | (((f >> 4) & 3) << 3);// 0..127
        _Float16 o[8];
        if (n < HH) {        // rows 0..255: W1a - W1b (multiplies x[dst])
            const float* a = W1 + (size_t)n * HH + k;
            #pragma unroll
            for (int j = 0; j < 8; ++j) o[j] = (_Float16)(a[j] - a[FF + j]);
        } else {             // rows 256..511: W1b (multiplies x[src])
            const float* a = W1 + (size_t)(n - HH) * HH + FF + k;
            #pragma unroll
            for (int j = 0; j < 8; ++j) o[j] = (_Float16)a[j];
        }
        __builtin_memcpy(wcf + (size_t)f * 8, o, 16);
    } else {                                            // W3 fragments (KB=8)
        const int f = (b - (PB_HIST + PB_W2 + PB_WC)) * 256 + t;    // 0..4095
        const int n = ((f >> 9) << 4) | (f & 15);                   // 0..127
        const int k = (((f >> 6) & 7) << 5) | (((f >> 4) & 3) << 3);
        const float* s = W3 + (size_t)n * HH + k;
        _Float16 o[8];
        #pragma unroll
        for (int j = 0; j < 8; ++j) o[j] = (_Float16)s[j];
        __builtin_memcpy(w3f + (size_t)f * 8, o, 16);
    }
}

// Node precompute: PQ'[i][0:256] = s1*(x@(W1a-W1b)^T) + c1 ; PQ'[i][256:512] = s1*(x@W1b^T)
// 32 nodes/block (625 blocks exactly covers NN); block NODEB is the scan block.
__global__ __launch_bounds__(512) void node_kernel(
    const float* __restrict__ x, const _Float16* __restrict__ wcf,
    const float* __restrict__ b1, const float* __restrict__ g1,
    const float* __restrict__ be1, const float* __restrict__ rm1,
    const float* __restrict__ rv1,
    _Float16* __restrict__ PQ,
    const int* __restrict__ cnt, int* __restrict__ wptr)
{
    if (blockIdx.x == NODEB) {   // exclusive prefix sum cnt -> wptr
        __shared__ int sp[512];
        const int t = threadIdx.x;
        const int base = t * 40;                  // 512*40 = 20480 >= NN
        int s = 0;
        #pragma unroll 1
        for (int g = 0; g < 5; ++g) {
            int v[8];
            #pragma unroll
            for (int u = 0; u < 8; ++u) {
                const int idx = base + g * 8 + u;
                v[u] = (idx < NN) ? cnt[idx] : 0;
            }
            #pragma unroll
            for (int u = 0; u < 8; ++u) s += v[u];
        }
        sp[t] = s;
        __syncthreads();
        for (int d = 1; d < 512; d <<= 1) {
            const int v = (t >= d) ? sp[t - d] : 0;
            __syncthreads();
            sp[t] += v;
            __syncthreads();
        }
        int run = sp[t] - s;
        #pragma unroll 1
        for (int g = 0; g < 5; ++g) {
            int v[8];
            #pragma unroll
            for (int u = 0; u < 8; ++u) {
                const int idx = base + g * 8 + u;
                v[u] = (idx < NN) ? cnt[idx] : 0;
            }
            #pragma unroll
            for (int u = 0; u < 8; ++u) {
                const int idx = base + g * 8 + u;
                if (idx < NN) { wptr[idx] = run; run += v[u]; }
            }
        }
        return;
    }

    const int tid = threadIdx.x;
    const int lane = tid & 63, wv = tid >> 6;     // wave owns 64 output channels
    const int lr = lane & 15, lq = lane >> 4;
    const int node0 = blockIdx.x * 32;            // 625 * 32 == 20000 exactly

    f32x4 acc[2][4];
    #pragma unroll
    for (int i = 0; i < 2; ++i)
        #pragma unroll
        for (int j = 0; j < 4; ++j) acc[i][j] = (f32x4){0.f, 0.f, 0.f, 0.f};

    const f16x8* wb = (const f16x8*)wcf + (size_t)(wv * 16) * 64 + lane;
    #pragma unroll 1
    for (int kb = 0; kb < 4; ++kb) {
        f16x8 wf[4], af[2];
        #pragma unroll
        for (int j = 0; j < 4; ++j) wf[j] = wb[(j * 4 + kb) * 64];
        #pragma unroll
        for (int i = 0; i < 2; ++i) {
            const int nd = node0 + i * 16 + lr;   // always < NN (exact tiling)
            const float* xp = x + (size_t)nd * FF + kb * 32 + lq * 8;
            const float4 xa = *(const float4*)xp;
            const float4 xb = *(const float4*)(xp + 4);
            f16x8 a;
            a[0] = (_Float16)xa.x; a[1] = (_Float16)xa.y;
            a[2] = (_Float16)xa.z; a[3] = (_Float16)xa.w;
            a[4] = (_Float16)xb.x; a[5] = (_Float16)xb.y;
            a[6] = (_Float16)xb.z; a[7] = (_Float16)xb.w;
            af[i] = a;
        }
        #pragma unroll
        for (int i = 0; i < 2; ++i)
            #pragma unroll
            for (int j = 0; j < 4; ++j)   // swapped operands: lane holds 4 consecutive n
                acc[i][j] = __builtin_amdgcn_mfma_f32_16x16x32_f16(wf[j], af[i], acc[i][j], 0, 0, 0);
    }

    #pragma unroll
    for (int j = 0; j < 4; ++j) {
        const int n0 = wv * 64 + j * 16 + lq * 4;
        const int ch = (n0 < HH) ? n0 : n0 - HH;
        float sc[4], cc[4];
        #pragma unroll
        for (int r = 0; r < 4; ++r) {
            const float s1 = g1[ch + r] * rsqrtf(rv1[ch + r] + 1e-5f);
            sc[r] = s1;
            cc[r] = (n0 < HH) ? (b1[ch + r] - rm1[ch + r]) * s1 + be1[ch + r] : 0.f;
        }
        #pragma unroll
        for (int i = 0; i < 2; ++i) {
            const int nd = node0 + i * 16 + lr;
            f16x4 o;
            #pragma unroll
            for (int r = 0; r < 4; ++r) o[r] = (_Float16)(acc[i][j][r] * sc[r] + cc[r]);
            *(f16x4*)(PQ + (size_t)nd * 512 + n0) = o;
        }
    }
}

// scatter + zero-out (out must be zero before fused's atomics; folded here)
__global__ __launch_bounds__(256) void scatter_kernel(const int* __restrict__ eidx,
                                                      int* __restrict__ wptr,
                                                      unsigned int* __restrict__ spair,
                                                      float* __restrict__ outp)
{
    const int idx = blockIdx.x * 256 + threadIdx.x;
    float4* o4 = (float4*)outp;
    #pragma unroll
    for (int i = 0; i < 2; ++i)
        o4[idx + i * 320000] = (float4){0.f, 0.f, 0.f, 0.f};   // 640000 float4 total
    if (idx < EE) {
        const int d = eidx[EE + idx];
        const int pos = atomicAdd(&wptr[d], 1);
        spair[pos] = (unsigned int)eidx[idx] | ((unsigned int)d << 16);
    }
}

// 256 threads (4 waves), MT=64, ~34 KB LDS -> 4 blocks/CU. [r12 structure]
// Stage-2 BN scale folded into w2f at prep -> epilogue = relu(acc + c2'),
// no per-block rsqrt preamble, no s_scale buffer.
__global__ __launch_bounds__(256, 4) void fused_edge_mlp(
    const _Float16* __restrict__ PQ,
    const unsigned int* __restrict__ spair,
    const _Float16* __restrict__ W2f,
    const float* __restrict__ c2p,
    const _Float16* __restrict__ W3f,
    float* __restrict__ outp)
{
    __shared__ __align__(16) char shb[MT * 512];   // 32 KiB: f16 [64][256] / fp32 [64][128]
    __shared__ __align__(16) float s_c[HH];
    __shared__ int s_dst[MT];
    // total LDS ~ 34 KB -> 4 blocks/CU

    const int tid = threadIdx.x;
    const int lane = tid & 63, wv = tid >> 6;     // wv 0..3
    const int lr = lane & 15, lq = lane >> 4;

    // bijective XCD swizzle (5000 = 8*625 exactly)
    const int swz = (blockIdx.x & 7) * 625 + (blockIdx.x >> 3);
    const int e0 = swz * MT;

    // ---- gather: h1 = relu(P'[dst] + Q'[src]) -> swizzled f16 [64][256]
    {
        const int r = wv * 16 + lr;               // 0..63
        const int q = lq;
        const unsigned int pv = spair[e0 + r];
        const int dr = (int)(pv >> 16), sr = (int)(pv & 0xffffu);
        const f16x8* pd = (const f16x8*)(PQ + (size_t)dr * 512 + q * 64);
        const f16x8* ps = (const f16x8*)(PQ + (size_t)sr * 512 + 256 + q * 64);
        f16x8 av[8], bv[8];
        #pragma unroll
        for (int i = 0; i < 8; ++i) av[i] = pd[i];        // issue all 16 loads up front
        #pragma unroll
        for (int i = 0; i < 8; ++i) bv[i] = ps[i];

        if (tid < MT) s_dst[tid] = (int)(spair[e0 + tid] >> 16);
        s_c[tid] = c2p[tid];                      // tid covers 0..255 == HH

        #pragma unroll
        for (int i = 0; i < 8; ++i) {
            f16x8 s = av[i] + bv[i];                      // v_pk_add_f16
            f16x8 o;
            #pragma unroll
            for (int j = 0; j < 8; ++j) {
                const _Float16 z = (_Float16)0;
                o[j] = s[j] > z ? s[j] : z;               // v_pk_max_f16
            }
            *(f16x8*)(shb + HADDR(r, q * 128 + i * 16)) = o;
        }
    }
    __syncthreads();

    {   // ---- stage 2: h2 = relu(h1 @ W2'^T + c2'), in place; 1m x 4n wave grid
        // wave = 64 rows x 64 cols: each af LDS read feeds 4 MFMAs; W2 read once
        // per block, 1-deep prefetched from L2 (fragment-major, s2 pre-scaled).
        const int wn = wv;
        f32x4 acc[4][4];
        #pragma unroll
        for (int i = 0; i < 4; ++i)
            #pragma unroll
            for (int j = 0; j < 4; ++j) acc[i][j] = (f32x4){0.f, 0.f, 0.f, 0.f};

        const f16x8* wbase = (const f16x8*)W2f + lane;
        f16x8 cw[4];
        #pragma unroll
        for (int j = 0; j < 4; ++j) cw[j] = wbase[((wn * 4 + j) * 8) * 64];
        __builtin_amdgcn_s_setprio(1);
        #pragma unroll 1
        for (int kb = 0; kb < 8; ++kb) {
            f16x8 nw[4];                                   // prefetch next kb (last over-reads: harmless)
            #pragma unroll
            for (int j = 0; j < 4; ++j) nw[j] = wbase[((wn * 4 + j) * 8 + kb + 1) * 64];
            f16x8 af[4];
            #pragma unroll
            for (int i = 0; i < 4; ++i)
                af[i] = *(const f16x8*)(shb + HADDR(i * 16 + lr, kb * 64 + lq * 16));
            #pragma unroll
            for (int i = 0; i < 4; ++i)
                #pragma unroll
                for (int j = 0; j < 4; ++j)
                    acc[i][j] = __builtin_amdgcn_mfma_f32_16x16x32_f16(cw[j], af[i], acc[i][j], 0, 0, 0);
            #pragma unroll
            for (int j = 0; j < 4; ++j) cw[j] = nw[j];
        }
        __builtin_amdgcn_s_setprio(0);
        __syncthreads();   // all reads of h1 done -> safe to overwrite in place
        #pragma unroll
        for (int j = 0; j < 4; ++j) {
            const int n0 = wn * 64 + j * 16 + lq * 4;     // 4 consecutive channels/lane
            const float4 cc4 = *(const float4*)&s_c[n0];
            #pragma unroll
            for (int i = 0; i < 4; ++i) {
                const int m = i * 16 + lr;
                f16x4 o;
                o[0] = (_Float16)fmaxf(acc[i][j][0] + cc4.x, 0.f);
                o[1] = (_Float16)fmaxf(acc[i][j][1] + cc4.y, 0.f);
                o[2] = (_Float16)fmaxf(acc[i][j][2] + cc4.z, 0.f);
                o[3] = (_Float16)fmaxf(acc[i][j][3] + cc4.w, 0.f);
                *(f16x4*)(shb + HADDR(m, n0 * 2)) = o;    // packed 8 B store
            }
        }
        __syncthreads();
    }

    {   // ---- stage 3: [64x256] @ W3^T -> fp32 tile -> segmented scatter-add; 2m x 2n grid
        // wave = 32 rows x 64 cols: each af read feeds 4 MFMAs; W3 read 2x/block, prefetched.
        const int wm = wv >> 1, wn = wv & 1;
        const int m_base = wm * 32;
        f32x4 acc[2][4];
        #pragma unroll
        for (int i = 0; i < 2; ++i)
            #pragma unroll
            for (int j = 0; j < 4; ++j) acc[i][j] = (f32x4){0.f, 0.f, 0.f, 0.f};

        const f16x8* wbase = (const f16x8*)W3f + lane;
        f16x8 cw[4];
        #pragma unroll
        for (int j = 0; j < 4; ++j) cw[j] = wbase[((wn * 4 + j) * 8) * 64];
        __builtin_amdgcn_s_setprio(1);
        #pragma unroll 1
        for (int kb = 0; kb < 8; ++kb) {
            f16x8 nw[4];                                   // last iter over-reads into wcf: harmless
            #pragma unroll
            for (int j = 0; j < 4; ++j) nw[j] = wbase[((wn * 4 + j) * 8 + kb + 1) * 64];
            f16x8 af[2];
            #pragma unroll
            for (int i = 0; i < 2; ++i)
                af[i] = *(const f16x8*)(shb + HADDR(m_base + i * 16 + lr, kb * 64 + lq * 16));
            #pragma unroll
            for (int i = 0; i < 2; ++i)
                #pragma unroll
                for (int j = 0; j < 4; ++j)
                    acc[i][j] = __builtin_amdgcn_mfma_f32_16x16x32_f16(cw[j], af[i], acc[i][j], 0, 0, 0);
            #pragma unroll
            for (int j = 0; j < 4; ++j) cw[j] = nw[j];
        }
        __builtin_amdgcn_s_setprio(0);
        __syncthreads();   // K-loop reads done before fp32 reuse of shb
        #pragma unroll
        for (int j = 0; j < 4; ++j) {
            const int n0 = wn * 64 + j * 16 + lq * 4;     // f32 col
            #pragma unroll
            for (int i = 0; i < 2; ++i) {
                const int m = m_base + i * 16 + lr;
                *(f32x4*)(shb + HADDR(m, n0 * 4)) = acc[i][j];  // packed 16 B store
            }
        }
        __syncthreads();

        {   // sorted dst -> one atomic per (segment, col, chunk); batched loads
            const int col = tid & 127;                    // 0..127
            const int bc  = col * 4;
            const int r0  = (tid >> 7) * 32;              // 0 or 32
            int cur = s_dst[r0];
            float run = 0.f;
            #pragma unroll 1
            for (int g = 0; g < 4; ++g) {
                float v[8];
                #pragma unroll
                for (int u = 0; u < 8; ++u)
                    v[u] = *(const float*)(shb + HADDR(r0 + g * 8 + u, bc));
                #pragma unroll
                for (int u = 0; u < 8; ++u) {
                    const int r = r0 + g * 8 + u;
                    const int d = s_dst[r];              // wave-uniform
                    if (d != cur) {
                        atomicAdd(&outp[(size_t)cur * FF + col], run);
                        run = 0.f; cur = d;
                    }
                    run += v[u];
                }
            }
            atomicAdd(&outp[(size_t)cur * FF + col], run);
        }
    }
}

__global__ __launch_bounds__(256) void finalize_kernel(const int* __restrict__ cnt,
                                                       const float* __restrict__ b3,
                                                       float* __restrict__ out)
{
    const int i4 = (blockIdx.x * 256 + threadIdx.x) * 4;
    if (i4 < NN * FF) {
        const float c = fmaxf((float)cnt[i4 >> 7], 1.0f);   // 4 | 128 -> same node for all 4
        const float rc = 1.0f / c;
        float4 v = *(const float4*)(out + i4);
        const float* bb = b3 + (i4 & 127);
        v.x = tanhf(v.x * rc + bb[0]);
        v.y = tanhf(v.y * rc + bb[1]);
        v.z = tanhf(v.z * rc + bb[2]);
        v.w = tanhf(v.w * rc + bb[3]);
        *(float4*)(out + i4) = v;
    }
}

extern "C" void kernel_launch(void* const* d_in, const int* in_sizes, int n_in,
                              void* d_out, int out_size, void* d_ws, size_t ws_size,
                              hipStream_t stream)
{
    const float* x   = (const float*)d_in[0];
    const int*   ei  = (const int*)d_in[1];
    const float* W1  = (const float*)d_in[2];
    const float* b1  = (const float*)d_in[3];
    const float* g1  = (const float*)d_in[4];
    const float* be1 = (const float*)d_in[5];
    const float* rm1 = (const float*)d_in[6];
    const float* rv1 = (const float*)d_in[7];
    const float* W2  = (const float*)d_in[8];
    const float* b2  = (const float*)d_in[9];
    const float* g2  = (const float*)d_in[10];
    const float* be2 = (const float*)d_in[11];
    const float* rm2 = (const float*)d_in[12];
    const float* rv2 = (const float*)d_in[13];
    const float* W3  = (const float*)d_in[14];
    const float* b3  = (const float*)d_in[15];

    char* ws = (char*)d_ws;
    int* cnt_i = (int*)ws;
    int* wptr  = (int*)(ws + WPTR_OFF);
    unsigned int* spair = (unsigned int*)(ws + SPAIR_OFF);
    float* c2p = (float*)(ws + C2P_OFF);
    _Float16* w2f = (_Float16*)(ws + W2F_OFF);
    _Float16* w3f = (_Float16*)(ws + W3F_OFF);
    _Float16* wcf = (_Float16*)(ws + WCF_OFF);
    _Float16* PQ  = (_Float16*)(ws + PQ_OFF);
    float* outp = (float*)d_out;

    hipMemsetAsync(cnt_i, 0, NN * sizeof(int), stream);

    prep_kernel<<<PREP_BLOCKS, 256, 0, stream>>>(ei, W1, W2, W3,
                                                 b2, g2, be2, rm2, rv2,
                                                 w2f, wcf, w3f, cnt_i, c2p);
    node_kernel<<<NODEB + 1, 512, 0, stream>>>(x, wcf, b1, g1, be1, rm1, rv1,
                                               PQ, cnt_i, wptr);
    scatter_kernel<<<(EE + 255) / 256, 256, 0, stream>>>(ei, wptr, spair, outp);
    fused_edge_mlp<<<NTILE, 256, 0, stream>>>(PQ, spair,
                                              w2f, c2p, w3f, outp);
    finalize_kernel<<<(NN * FF / 4 + 255) / 256, 256, 0, stream>>>(cnt_i, b3, outp);
}

// Round 15
// 260.320 us; speedup vs baseline: 1.0811x; 1.0004x over previous
//
#include <hip/hip_runtime.h>
#include <math.h>

#define NN 20000
#define EE 320000
#define FF 128
#define HH 256
#define MT 64        // edges per block (4 blocks/CU phase diversity)
#define NTILE 5000   // EE / MT exactly; 5000 = 8 * 625 -> clean XCD swizzle

typedef _Float16 f16x8 __attribute__((ext_vector_type(8)));
typedef _Float16 f16x4 __attribute__((ext_vector_type(4)));
typedef float    f32x4 __attribute__((ext_vector_type(4)));

// Conflict-free LDS: 64 rows x 512 B (row stride == 0 mod 32 banks), 16-B chunk
// XOR swizzle by (row&7).  [r12-measured optimum]
#define HADDR(m, bcol) (((m) << 9) + ((bcol) ^ (((m) & 7) << 4)))

// ---- workspace layout (bytes) ----
// cnt   : NN i32        @ 0
// wptr  : NN i32        @ 80,000
// spair : EE u32        @ 160,000      (src | dst<<16)
// c2p   : HH f32        @ 1,500,000    (folded BN bias, stage 2; 1 KB)
// c1p   : HH f32        @ 1,501,024    (folded BN bias, stage 1; 1 KB)
// w2f   : 8192 frags    @ 6,560,000    (16x16-frag-major s2-scaled W2 f16, KB=8)
// w3f   : 4096 frags    @ 6,691,072    (16x16-frag-major W3 f16, KB=8)
// wcf   : 8192 frags    @ 6,756,608    (16x16-frag-major s1-scaled [W1a-W1b ; W1b])
// PQ    : NN*512 f16    @ 6,887,680    (P' | Q' per node) end 27,367,680
// NOTE: K-loop W prefetch intentionally over-reads one kb past w2f/w3f ends ->
// lands in the adjacent workspace region (mapped, value unused).
#define WPTR_OFF  80000
#define SPAIR_OFF 160000
#define C2P_OFF   1500000
#define C1P_OFF   1501024
#define W2F_OFF   6560000
#define W3F_OFF   6691072
#define WCF_OFF   6756608
#define PQ_OFF    6887680

// prep roles (blocks of 256 threads)
#define PB_HIST 1250   // 320,000 hist atomics
#define PB_W2   32     // 8192 fragments (s2-scaled)
#define PB_WC   32     // 8192 fragments (s1-scaled)
#define PB_W3   16     // 4096 fragments
#define PREP_BLOCKS (PB_HIST + PB_W2 + PB_WC + PB_W3)

#define NODEB 625      // 20000/32 exactly; block NODEB is the scan block

// 16x16x32 fragment-major layout (all weight buffers):
//   frag f = (nt*8 + kb)*64 + lane, lane = lq*16 + lr
//   element (n, k): n = nt*16 + lr, k = kb*32 + lq*8 + j (j = 0..7)
// A wave's 64 lanes read frags[f0 + lane] -> one contiguous 1 KiB transaction.

__global__ __launch_bounds__(256) void prep_kernel(
    const int* __restrict__ eidx,
    const float* __restrict__ W1, const float* __restrict__ W2,
    const float* __restrict__ W3,
    const float* __restrict__ b1, const float* __restrict__ g1,
    const float* __restrict__ be1, const float* __restrict__ rm1,
    const float* __restrict__ rv1,
    const float* __restrict__ b2, const float* __restrict__ g2,
    const float* __restrict__ be2, const float* __restrict__ rm2,
    const float* __restrict__ rv2,
    _Float16* __restrict__ w2f, _Float16* __restrict__ wcf,
    _Float16* __restrict__ w3f, int* __restrict__ cnt,
    float* __restrict__ c2p, float* __restrict__ c1p)
{
    const int b = blockIdx.x, t = threadIdx.x;
    if (b < PB_HIST) {                                  // dst histogram
        const int e = b * 256 + t;
        atomicAdd(&cnt[eidx[EE + e]], 1);
    } else if (b < PB_HIST + PB_W2) {                   // s2-scaled W2 fragments (KB=8)
        const int f = (b - PB_HIST) * 256 + t;                      // 0..8191
        const int n = ((f >> 9) << 4) | (f & 15);                   // 0..255
        const int k = (((f >> 6) & 7) << 5) | (((f >> 4) & 3) << 3);
        const float s2n = g2[n] * rsqrtf(rv2[n] + 1e-5f);
        const float* s = W2 + (size_t)n * HH + k;
        _Float16 o[8];
        #pragma unroll
        for (int j = 0; j < 8; ++j) o[j] = (_Float16)(s2n * s[j]);
        __builtin_memcpy(w2f + (size_t)f * 8, o, 16);
        if (b == PB_HIST) {   // first W2 block also emits the folded stage-2 bias
            const float s2t = g2[t] * rsqrtf(rv2[t] + 1e-5f);
            c2p[t] = (b2[t] - rm2[t]) * s2t + be2[t];
        }
    } else if (b < PB_HIST + PB_W2 + PB_WC) {           // s1-scaled Wc fragments (KB=4)
        const int f = (b - (PB_HIST + PB_W2)) * 256 + t;            // 0..8191
        const int n = ((f >> 8) << 4) | (f & 15);                   // 0..511
        const int k = (((f >> 6) & 3) << 5) | (((f >> 4) & 3) << 3);// 0..127
        const int ch = (n < HH) ? n : n - HH;
        const float s1n = g1[ch] * rsqrtf(rv1[ch] + 1e-5f);
        _Float16 o[8];
        if (n < HH) {        // rows 0..255: s1*(W1a - W1b)  (multiplies x[dst])
            const float* a = W1 + (size_t)n * HH + k;
            #pragma unroll
            for (int j = 0; j < 8; ++j) o[j] = (_Float16)(s1n * (a[j] - a[FF + j]));
        } else {             // rows 256..511: s1*W1b        (multiplies x[src])
            const float* a = W1 + (size_t)(n - HH) * HH + FF + k;
            #pragma unroll
            for (int j = 0; j < 8; ++j) o[j] = (_Float16)(s1n * a[j]);
        }
        __builtin_memcpy(wcf + (size_t)f * 8, o, 16);
        if (b == PB_HIST + PB_W2) {   // first Wc block also emits the stage-1 bias
            const float s1t = g1[t] * rsqrtf(rv1[t] + 1e-5f);
            c1p[t] = (b1[t] - rm1[t]) * s1t + be1[t];
        }
    } else {                                            // W3 fragments (KB=8)
        const int f = (b - (PB_HIST + PB_W2 + PB_WC)) * 256 + t;    // 0..4095
        const int n = ((f >> 9) << 4) | (f & 15);                   // 0..127
        const int k = (((f >> 6) & 7) << 5) | (((f >> 4) & 3) << 3);
        const float* s = W3 + (size_t)n * HH + k;
        _Float16 o[8];
        #pragma unroll
        for (int j = 0; j < 8; ++j) o[j] = (_Float16)s[j];
        __builtin_memcpy(w3f + (size_t)f * 8, o, 16);
    }
}

// Node precompute: PQ'[i][0:256] = x@(s1*(W1a-W1b))^T + c1' ; PQ'[i][256:512] = x@(s1*W1b)^T
// BN scale pre-folded into wcf; epilogue = acc + c1' (no rsqrt).
// 32 nodes/block (625 blocks exactly covers NN); block NODEB is the scan block.
__global__ __launch_bounds__(512) void node_kernel(
    const float* __restrict__ x, const _Float16* __restrict__ wcf,
    const float* __restrict__ c1p,
    _Float16* __restrict__ PQ,
    const int* __restrict__ cnt, int* __restrict__ wptr)
{
    if (blockIdx.x == NODEB) {   // exclusive prefix sum cnt -> wptr
        __shared__ int sp[512];
        const int t = threadIdx.x;
        const int base = t * 40;                  // 512*40 = 20480 >= NN
        int s = 0;
        #pragma unroll 1
        for (int g = 0; g < 5; ++g) {
            int v[8];
            #pragma unroll
            for (int u = 0; u < 8; ++u) {
                const int idx = base + g * 8 + u;
                v[u] = (idx < NN) ? cnt[idx] : 0;
            }
            #pragma unroll
            for (int u = 0; u < 8; ++u) s += v[u];
        }
        sp[t] = s;
        __syncthreads();
        for (int d = 1; d < 512; d <<= 1) {
            const int v = (t >= d) ? sp[t - d] : 0;
            __syncthreads();
            sp[t] += v;
            __syncthreads();
        }
        int run = sp[t] - s;
        #pragma unroll 1
        for (int g = 0; g < 5; ++g) {
            int v[8];
            #pragma unroll
            for (int u = 0; u < 8; ++u) {
                const int idx = base + g * 8 + u;
                v[u] = (idx < NN) ? cnt[idx] : 0;
            }
            #pragma unroll
            for (int u = 0; u < 8; ++u) {
                const int idx = base + g * 8 + u;
                if (idx < NN) { wptr[idx] = run; run += v[u]; }
            }
        }
        return;
    }

    const int tid = threadIdx.x;
    const int lane = tid & 63, wv = tid >> 6;     // wave owns 64 output channels
    const int lr = lane & 15, lq = lane >> 4;
    const int node0 = blockIdx.x * 32;            // 625 * 32 == 20000 exactly

    f32x4 acc[2][4];
    #pragma unroll
    for (int i = 0; i < 2; ++i)
        #pragma unroll
        for (int j = 0; j < 4; ++j) acc[i][j] = (f32x4){0.f, 0.f, 0.f, 0.f};

    const f16x8* wb = (const f16x8*)wcf + (size_t)(wv * 16) * 64 + lane;
    #pragma unroll 1
    for (int kb = 0; kb < 4; ++kb) {
        f16x8 wf[4], af[2];
        #pragma unroll
        for (int j = 0; j < 4; ++j) wf[j] = wb[(j * 4 + kb) * 64];
        #pragma unroll
        for (int i = 0; i < 2; ++i) {
            const int nd = node0 + i * 16 + lr;   // always < NN (exact tiling)
            const float* xp = x + (size_t)nd * FF + kb * 32 + lq * 8;
            const float4 xa = *(const float4*)xp;
            const float4 xb = *(const float4*)(xp + 4);
            f16x8 a;
            a[0] = (_Float16)xa.x; a[1] = (_Float16)xa.y;
            a[2] = (_Float16)xa.z; a[3] = (_Float16)xa.w;
            a[4] = (_Float16)xb.x; a[5] = (_Float16)xb.y;
            a[6] = (_Float16)xb.z; a[7] = (_Float16)xb.w;
            af[i] = a;
        }
        #pragma unroll
        for (int i = 0; i < 2; ++i)
            #pragma unroll
            for (int j = 0; j < 4; ++j)   // swapped operands: lane holds 4 consecutive n
                acc[i][j] = __builtin_amdgcn_mfma_f32_16x16x32_f16(wf[j], af[i], acc[i][j], 0, 0, 0);
    }

    #pragma unroll
    for (int j = 0; j < 4; ++j) {
        const int n0 = wv * 64 + j * 16 + lq * 4;
        float4 cc4;
        if (n0 < HH) cc4 = *(const float4*)&c1p[n0];
        else         cc4 = (float4){0.f, 0.f, 0.f, 0.f};
        #pragma unroll
        for (int i = 0; i < 2; ++i) {
            const int nd = node0 + i * 16 + lr;
            f16x4 o;
            o[0] = (_Float16)(acc[i][j][0] + cc4.x);
            o[1] = (_Float16)(acc[i][j][1] + cc4.y);
            o[2] = (_Float16)(acc[i][j][2] + cc4.z);
            o[3] = (_Float16)(acc[i][j][3] + cc4.w);
            *(f16x4*)(PQ + (size_t)nd * 512 + n0) = o;
        }
    }
}

// scatter + zero-out (out must be zero before fused's atomics; folded here)
__global__ __launch_bounds__(256) void scatter_kernel(const int* __restrict__ eidx,
                                                      int* __restrict__ wptr,
                                                      unsigned int* __restrict__ spair,
                                                      float* __restrict__ outp)
{
    const int idx = blockIdx.x * 256 + threadIdx.x;
    float4* o4 = (float4*)outp;
    #pragma unroll
    for (int i = 0; i < 2; ++i)
        o4[idx + i * 320000] = (float4){0.f, 0.f, 0.f, 0.f};   // 640000 float4 total
    if (idx < EE) {
        const int d = eidx[EE + idx];
        const int pos = atomicAdd(&wptr[d], 1);
        spair[pos] = (unsigned int)eidx[idx] | ((unsigned int)d << 16);
    }
}

// 256 threads (4 waves), MT=64, ~34 KB LDS -> 4 blocks/CU. [r14 structure]
// Both BN scales folded into weights at prep; stage-2 epilogue = relu(acc+c2').
__global__ __launch_bounds__(256, 4) void fused_edge_mlp(
    const _Float16* __restrict__ PQ,
    const unsigned int* __restrict__ spair,
    const _Float16* __restrict__ W2f,
    const float* __restrict__ c2p,
    const _Float16* __restrict__ W3f,
    float* __restrict__ outp)
{
    __shared__ __align__(16) char shb[MT * 512];   // 32 KiB: f16 [64][256] / fp32 [64][128]
    __shared__ __align__(16) float s_c[HH];
    __shared__ int s_dst[MT];
    // total LDS ~ 34 KB -> 4 blocks/CU

    const int tid = threadIdx.x;
    const int lane = tid & 63, wv = tid >> 6;     // wv 0..3
    const int lr = lane & 15, lq = lane >> 4;

    // bijective XCD swizzle (5000 = 8*625 exactly)
    const int swz = (blockIdx.x & 7) * 625 + (blockIdx.x >> 3);
    const int e0 = swz * MT;

    // ---- gather: h1 = relu(P'[dst] + Q'[src]) -> swizzled f16 [64][256]
    {
        const int r = wv * 16 + lr;               // 0..63
        const int q = lq;
        const unsigned int pv = spair[e0 + r];
        const int dr = (int)(pv >> 16), sr = (int)(pv & 0xffffu);
        const f16x8* pd = (const f16x8*)(PQ + (size_t)dr * 512 + q * 64);
        const f16x8* ps = (const f16x8*)(PQ + (size_t)sr * 512 + 256 + q * 64);
        f16x8 av[8], bv[8];
        #pragma unroll
        for (int i = 0; i < 8; ++i) av[i] = pd[i];        // issue all 16 loads up front
        #pragma unroll
        for (int i = 0; i < 8; ++i) bv[i] = ps[i];

        if (tid < MT) s_dst[tid] = (int)(spair[e0 + tid] >> 16);
        s_c[tid] = c2p[tid];                      // tid covers 0..255 == HH

        #pragma unroll
        for (int i = 0; i < 8; ++i) {
            f16x8 s = av[i] + bv[i];                      // v_pk_add_f16
            f16x8 o;
            #pragma unroll
            for (int j = 0; j < 8; ++j) {
                const _Float16 z = (_Float16)0;
                o[j] = s[j] > z ? s[j] : z;               // v_pk_max_f16
            }
            *(f16x8*)(shb + HADDR(r, q * 128 + i * 16)) = o;
        }
    }
    __syncthreads();

    {   // ---- stage 2: h2 = relu(h1 @ W2'^T + c2'), in place; 1m x 4n wave grid
        // wave = 64 rows x 64 cols: each af LDS read feeds 4 MFMAs; W2 read once
        // per block, 1-deep prefetched from L2 (fragment-major, s2 pre-scaled).
        const int wn = wv;
        f32x4 acc[4][4];
        #pragma unroll
        for (int i = 0; i < 4; ++i)
            #pragma unroll
            for (int j = 0; j < 4; ++j) acc[i][j] = (f32x4){0.f, 0.f, 0.f, 0.f};

        const f16x8* wbase = (const f16x8*)W2f + lane;
        f16x8 cw[4];
        #pragma unroll
        for (int j = 0; j < 4; ++j) cw[j] = wbase[((wn * 4 + j) * 8) * 64];
        __builtin_amdgcn_s_setprio(1);
        #pragma unroll 1
        for (int kb = 0; kb < 8; ++kb) {
            f16x8 nw[4];                                   // prefetch next kb (last over-reads: harmless)
            #pragma unroll
            for (int j = 0; j < 4; ++j) nw[j] = wbase[((wn * 4 + j) * 8 + kb + 1) * 64];
            f16x8 af[4];
            #pragma unroll
            for (int i = 0; i < 4; ++i)
                af[i] = *(const f16x8*)(shb + HADDR(i * 16 + lr, kb * 64 + lq * 16));
            #pragma unroll
            for (int i = 0; i < 4; ++i)
                #pragma unroll
                for (int j = 0; j < 4; ++j)
                    acc[i][j] = __builtin_amdgcn_mfma_f32_16x16x32_f16(cw[j], af[i], acc[i][j], 0, 0, 0);
            #pragma unroll
            for (int j = 0; j < 4; ++j) cw[j] = nw[j];
        }
        __builtin_amdgcn_s_setprio(0);
        __syncthreads();   // all reads of h1 done -> safe to overwrite in place
        #pragma unroll
        for (int j = 0; j < 4; ++j) {
            const int n0 = wn * 64 + j * 16 + lq * 4;     // 4 consecutive channels/lane
            const float4 cc4 = *(const float4*)&s_c[n0];
            #pragma unroll
            for (int i = 0; i < 4; ++i) {
                const int m = i * 16 + lr;
                f16x4 o;
                o[0] = (_Float16)fmaxf(acc[i][j][0] + cc4.x, 0.f);
                o[1] = (_Float16)fmaxf(acc[i][j][1] + cc4.y, 0.f);
                o[2] = (_Float16)fmaxf(acc[i][j][2] + cc4.z, 0.f);
                o[3] = (_Float16)fmaxf(acc[i][j][3] + cc4.w, 0.f);
                *(f16x4*)(shb + HADDR(m, n0 * 2)) = o;    // packed 8 B store
            }
        }
        __syncthreads();
    }

    {   // ---- stage 3: [64x256] @ W3^T -> fp32 tile -> segmented scatter-add; 2m x 2n grid
        // wave = 32 rows x 64 cols: each af read feeds 4 MFMAs; W3 read 2x/block, prefetched.
        const int wm = wv >> 1, wn = wv & 1;
        const int m_base = wm * 32;
        f32x4 acc[2][4];
        #pragma unroll
        for (int i = 0; i < 2; ++i)
            #pragma unroll
            for (int j = 0; j < 4; ++j) acc[i][j] = (f32x4){0.f, 0.f, 0.f, 0.f};

        const f16x8* wbase = (const f16x8*)W3f + lane;
        f16x8 cw[4];
        #pragma unroll
        for (int j = 0; j < 4; ++j) cw[j] = wbase[((wn * 4 + j) * 8) * 64];
        __builtin_amdgcn_s_setprio(1);
        #pragma unroll 1
        for (int kb = 0; kb < 8; ++kb) {
            f16x8 nw[4];                                   // last iter over-reads into wcf: harmless
            #pragma unroll
            for (int j = 0; j < 4; ++j) nw[j] = wbase[((wn * 4 + j) * 8 + kb + 1) * 64];
            f16x8 af[2];
            #pragma unroll
            for (int i = 0; i < 2; ++i)
                af[i] = *(const f16x8*)(shb + HADDR(m_base + i * 16 + lr, kb * 64 + lq * 16));
            #pragma unroll
            for (int i = 0; i < 2; ++i)
                #pragma unroll
                for (int j = 0; j < 4; ++j)
                    acc[i][j] = __builtin_amdgcn_mfma_f32_16x16x32_f16(cw[j], af[i], acc[i][j], 0, 0, 0);
            #pragma unroll
            for (int j = 0; j < 4; ++j) cw[j] = nw[j];
        }
        __builtin_amdgcn_s_setprio(0);
        __syncthreads();   // K-loop reads done before fp32 reuse of shb
        #pragma unroll
        for (int j = 0; j < 4; ++j) {
            const int n0 = wn * 64 + j * 16 + lq * 4;     // f32 col
            #pragma unroll
            for (int i = 0; i < 2; ++i) {
                const int m = m_base + i * 16 + lr;
                *(f32x4*)(shb + HADDR(m, n0 * 4)) = acc[i][j];  // packed 16 B store
            }
        }
        __syncthreads();

        {   // sorted dst -> one atomic per (segment, col, chunk); batched loads
            const int col = tid & 127;                    // 0..127
            const int bc  = col * 4;
            const int r0  = (tid >> 7) * 32;              // 0 or 32
            int cur = s_dst[r0];
            float run = 0.f;
            #pragma unroll 1
            for (int g = 0; g < 4; ++g) {
                float v[8];
                #pragma unroll
                for (int u = 0; u < 8; ++u)
                    v[u] = *(const float*)(shb + HADDR(r0 + g * 8 + u, bc));
                #pragma unroll
                for (int u = 0; u < 8; ++u) {
                    const int r = r0 + g * 8 + u;
                    const int d = s_dst[r];              // wave-uniform
                    if (d != cur) {
                        atomicAdd(&outp[(size_t)cur * FF + col], run);
                        run = 0.f; cur = d;
                    }
                    run += v[u];
                }
            }
            atomicAdd(&outp[(size_t)cur * FF + col], run);
        }
    }
}

__global__ __launch_bounds__(256) void finalize_kernel(const int* __restrict__ cnt,
                                                       const float* __restrict__ b3,
                                                       float* __restrict__ out)
{
    const int i4 = (blockIdx.x * 256 + threadIdx.x) * 4;
    if (i4 < NN * FF) {
        const float c = fmaxf((float)cnt[i4 >> 7], 1.0f);   // 4 | 128 -> same node for all 4
        const float rc = 1.0f / c;
        float4 v = *(const float4*)(out + i4);
        const float* bb = b3 + (i4 & 127);
        v.x = tanhf(v.x * rc + bb[0]);
        v.y = tanhf(v.y * rc + bb[1]);
        v.z = tanhf(v.z * rc + bb[2]);
        v.w = tanhf(v.w * rc + bb[3]);
        *(float4*)(out + i4) = v;
    }
}

extern "C" void kernel_launch(void* const* d_in, const int* in_sizes, int n_in,
                              void* d_out, int out_size, void* d_ws, size_t ws_size,
                              hipStream_t stream)
{
    const float* x   = (const float*)d_in[0];
    const int*   ei  = (const int*)d_in[1];
    const float* W1  = (const float*)d_in[2];
    const float* b1  = (const float*)d_in[3];
    const float* g1  = (const float*)d_in[4];
    const float* be1 = (const float*)d_in[5];
    const float* rm1 = (const float*)d_in[6];
    const float* rv1 = (const float*)d_in[7];
    const float* W2  = (const float*)d_in[8];
    const float* b2  = (const float*)d_in[9];
    const float* g2  = (const float*)d_in[10];
    const float* be2 = (const float*)d_in[11];
    const float* rm2 = (const float*)d_in[12];
    const float* rv2 = (const float*)d_in[13];
    const float* W3  = (const float*)d_in[14];
    const float* b3  = (const float*)d_in[15];

    char* ws = (char*)d_ws;
    int* cnt_i = (int*)ws;
    int* wptr  = (int*)(ws + WPTR_OFF);
    unsigned int* spair = (unsigned int*)(ws + SPAIR_OFF);
    float* c2p = (float*)(ws + C2P_OFF);
    float* c1p = (float*)(ws + C1P_OFF);
    _Float16* w2f = (_Float16*)(ws + W2F_OFF);
    _Float16* w3f = (_Float16*)(ws + W3F_OFF);
    _Float16* wcf = (_Float16*)(ws + WCF_OFF);
    _Float16* PQ  = (_Float16*)(ws + PQ_OFF);
    float* outp = (float*)d_out;

    hipMemsetAsync(cnt_i, 0, NN * sizeof(int), stream);

    prep_kernel<<<PREP_BLOCKS, 256, 0, stream>>>(ei, W1, W2, W3,
                                                 b1, g1, be1, rm1, rv1,
                                                 b2, g2, be2, rm2, rv2,
                                                 w2f, wcf, w3f, cnt_i, c2p, c1p);
    node_kernel<<<NODEB + 1, 512, 0, stream>>>(x, wcf, c1p, PQ, cnt_i, wptr);
    scatter_kernel<<<(EE + 255) / 256, 256, 0, stream>>>(ei, wptr, spair, outp);
    fused_edge_mlp<<<NTILE, 256, 0, stream>>>(PQ, spair,
                                              w2f, c2p, w3f, outp);
    finalize_kernel<<<(NN * FF / 4 + 255) / 256, 256, 0, stream>>>(cnt_i, b3, outp);
}